// Round 7
// baseline (222.868 us; speedup 1.0000x reference)
//
#include <hip/hip_runtime.h>

#define BLOCK 256
#define NB    2048          // 8 blocks/CU, grid exactly resident

// Native clang vector types (nontemporal builtin rejects HIP_vector_type).
typedef float fx4 __attribute__((ext_vector_type(4)));
typedef int   ix4 __attribute__((ext_vector_type(4)));

// Branch-free BCE matching jnp: -(t*clip(log p,-100) + (1-t)*clip(log1p(-p),-100))
__device__ __forceinline__ float bce_elem(float p, float t) {
    float lp  = fmaxf(__logf(p), -100.0f);
    float l1p = fmaxf(__logf(1.0f - p), -100.0f);
    return -__builtin_fmaf(t, lp - l1p, l1p);
}

// Round-7 == round-6 resubmit (infra failure, kernel never ran).
// Copy-shaped slab sweep: r0-r5 established that search depth, per-wave
// pipeline depth, and nt-allocation are all null; the block-per-segment
// structure (2048 private 47KB ranges, 3.8 trips/thread, ragged heads) is
// the last suspect for streaming at 3.2 TB/s while copy/fill do 6.3-6.6 in
// this same environment. Whole grid sweeps contiguous slabs of all four
// arrays (batch streamed instead of searched); segment routing via wave-
// uniform detection -> one atomicAdd pair per wave (~93% of waves), per-lane
// fallback at the 2047 boundaries. NO fences, NO last-block fusion (r3: agent
// fences on 8-XCD = L2 writeback storm, 5x regression).
__global__ __launch_bounds__(BLOCK, 8) void stream_kernel(
    const float* __restrict__ pred, const float* __restrict__ tgt,
    const int* __restrict__ batch, const int* __restrict__ mask,
    float* __restrict__ acc_b, float* __restrict__ acc_c, int n)
{
    const int tid  = blockIdx.x * BLOCK + threadIdx.x;
    const int lane = threadIdx.x & 63;
    const int ngroups  = n >> 2;
    const int nthreads = NB * BLOCK;

    const fx4* p4 = reinterpret_cast<const fx4*>(pred);
    const fx4* t4 = reinterpret_cast<const fx4*>(tgt);
    const ix4* m4 = reinterpret_cast<const ix4*>(mask);
    const ix4* b4 = reinterpret_cast<const ix4*>(batch);

    for (int g = tid; g < ngroups; g += nthreads) {
        fx4 p = __builtin_nontemporal_load(p4 + g);
        fx4 t = __builtin_nontemporal_load(t4 + g);
        ix4 m = __builtin_nontemporal_load(m4 + g);
        ix4 s = __builtin_nontemporal_load(b4 + g);

        float m0 = (float)m[0], m1 = (float)m[1],
              m2 = (float)m[2], m3 = (float)m[3];
        float v0 = bce_elem(p[0] * m0, t[0]);
        float v1 = bce_elem(p[1] * m1, t[1]);
        float v2 = bce_elem(p[2] * m2, t[2]);
        float v3 = bce_elem(p[3] * m3, t[3]);
        float vb = (v0 + v1) + (v2 + v3);
        float vc = (m0 + m1) + (m2 + m3);

        // Wave covers 256 consecutive elements (lanes have consecutive g).
        // If lane0's first seg == lane63's last seg, whole wave is one segment.
        const int  wave_base = g - lane;
        const bool wave_full = (wave_base + 63) < ngroups;   // partial only at array end
        const int  slo = __shfl(s[0], 0);
        const int  shi = __shfl(s[3], 63);                   // unused if !wave_full

        if (wave_full && slo == shi) {
            #pragma unroll
            for (int o = 32; o > 0; o >>= 1) {
                vb += __shfl_xor(vb, o);
                vc += __shfl_xor(vc, o);
            }
            if (lane == 0) {
                atomicAdd(&acc_b[slo], vb);
                atomicAdd(&acc_c[slo], vc);
            }
        } else if (s[0] == s[3]) {           // lane's 4 elems in one segment
            atomicAdd(&acc_b[s[0]], vb);
            atomicAdd(&acc_c[s[0]], vc);
        } else {                             // straddling lane (rare)
            atomicAdd(&acc_b[s[0]], v0);  atomicAdd(&acc_c[s[0]], m0);
            atomicAdd(&acc_b[s[1]], v1);  atomicAdd(&acc_c[s[1]], m1);
            atomicAdd(&acc_b[s[2]], v2);  atomicAdd(&acc_c[s[2]], m2);
            atomicAdd(&acc_b[s[3]], v3);  atomicAdd(&acc_c[s[3]], m3);
        }
    }

    // generic tail for n % 4 != 0 (N=8M: empty)
    if (tid == 0) {
        for (int i = (ngroups << 2); i < n; ++i) {
            float mf = (float)mask[i];
            atomicAdd(&acc_b[batch[i]], bce_elem(pred[i] * mf, tgt[i]));
            atomicAdd(&acc_c[batch[i]], mf);
        }
    }
}

// Separate finalize dispatch (kernel boundary = device-wide visibility of the
// atomics; no fences needed). per_graph math + sat term + total sum.
__global__ __launch_bounds__(256) void finalize_kernel(
    const float* __restrict__ acc_b, const float* __restrict__ acc_c,
    const float* __restrict__ sat_pred, const float* __restrict__ sat_tgt,
    float* __restrict__ out, int Bseg)
{
    float local = 0.0f;
    for (int i = threadIdx.x; i < Bseg; i += 256) {
        float c  = acc_c[i];
        float pg = (c > 0.0f) ? acc_b[i] / fmaxf(c, 1.0f) : 0.0f;
        pg += bce_elem(sat_pred[i], sat_tgt[i]) * ((1.0f / 50.0f) / (float)Bseg);
        local += pg;
    }
    #pragma unroll
    for (int o = 32; o > 0; o >>= 1) local += __shfl_xor(local, o);
    __shared__ float ws[4];
    if ((threadIdx.x & 63) == 0) ws[threadIdx.x >> 6] = local;
    __syncthreads();
    if (threadIdx.x == 0) out[0] = ws[0] + ws[1] + ws[2] + ws[3];
}

extern "C" void kernel_launch(void* const* d_in, const int* in_sizes, int n_in,
                              void* d_out, int out_size, void* d_ws, size_t ws_size,
                              hipStream_t stream) {
    const float* y_mus_pred = (const float*)d_in[0];
    const float* y_mus      = (const float*)d_in[1];
    const float* y_sat_pred = (const float*)d_in[2];
    const float* y_sat      = (const float*)d_in[3];
    const int*   batch      = (const int*)d_in[4];
    const int*   mask       = (const int*)d_in[5];

    const int n    = in_sizes[0];
    const int Bseg = in_sizes[2];

    float* acc_b = (float*)d_ws;          // [Bseg] BCE sums
    float* acc_c = acc_b + Bseg;          // [Bseg] mask counts

    hipMemsetAsync(acc_b, 0, 2 * Bseg * sizeof(float), stream);  // capture-safe
    stream_kernel<<<NB, BLOCK, 0, stream>>>(
        y_mus_pred, y_mus, batch, mask, acc_b, acc_c, n);
    finalize_kernel<<<1, 256, 0, stream>>>(
        acc_b, acc_c, y_sat_pred, y_sat, (float*)d_out, Bseg);
}

// Round 8
// 153.910 us; speedup vs baseline: 1.4480x; 1.4480x over previous
//
#include <hip/hip_runtime.h>

#define BLOCK 128           // 2 waves/block; 2048 blocks -> 8 blocks/CU resident
#define NW    2             // waves per block
#define TILE  256           // elements per DMA tile = 1 KB per array per wave

// Native clang vector type (16B LDS reads).
typedef float fx4 __attribute__((ext_vector_type(4)));

// Async global->LDS DMA, 16B per lane per inst (64 lanes -> 1 KB).
// LDS dest is wave-uniform base + lane*16 (HW rule); global src is per-lane.
// Address-space casts go through uintptr_t (CK idiom; C-style AS casts are
// rejected by clang++). Generic LDS pointer truncates to the LDS offset.
#define GLD16(gp, lp)                                                          \
    __builtin_amdgcn_global_load_lds(                                          \
        (const __attribute__((address_space(1))) void*)(uintptr_t)(gp),        \
        (__attribute__((address_space(3))) void*)(uintptr_t)(lp), 16, 0, 0)

// Branch-free BCE matching jnp: -(t*clip(log p,-100) + (1-t)*clip(log1p(-p),-100))
__device__ __forceinline__ float bce_elem(float p, float t) {
    float lp  = fmaxf(__logf(p), -100.0f);
    float l1p = fmaxf(__logf(1.0f - p), -100.0f);
    return -__builtin_fmaf(t, lp - l1p, l1p);
}

// Wave-cooperative lower_bound: first i in [0,n) with a[i] >= v (a ascending).
__device__ __forceinline__ int wave_lower_bound(const int* __restrict__ a, int n, int v) {
    const int lane = threadIdx.x & 63;
    int lo = 0, hi = n;
    while (hi - lo > 64) {
        int range  = hi - lo;
        int stride = range / 65 + 1;
        int idx    = lo + (lane + 1) * stride;
        bool lt    = (idx < hi) && (a[idx] < v);
        int  c     = __popcll(__ballot(lt));
        int  nlo   = lo + c * stride;
        int  nhi   = nlo + stride;
        if (nhi > hi) nhi = hi;
        lo = nlo; hi = nhi;
    }
    int idx = lo + lane;
    bool ge = (idx >= hi) || (a[idx] >= v);
    unsigned long long bal = __ballot(ge);
    return bal ? (lo + __ffsll(bal) - 1) : hi;
}

// Block-per-segment (r7: copy-shape+atomics = 100us even cached -> reverted).
// Round-8: DMA-staged stream. r0-r7 model fit: BW = waves/CU*256*inflight/220ns
// (1-deep=1.5, 2-deep=2.2 TB/s observed). Register pipelines lose the VGPR/
// scheduler fight, so stage via global_load_lds (0 VGPRs, deep queue):
// wave-private double-buffered 1KB-per-array tiles -> 3KB/wave in flight,
// counted s_waitcnt vmcnt(3) (never 0 mid-loop), NO barriers in the loop.
__global__ __launch_bounds__(BLOCK, 4) void seg_kernel(
    const float* __restrict__ pred, const float* __restrict__ tgt,
    const int* __restrict__ batch, const int* __restrict__ mask,
    const float* __restrict__ sat_pred, const float* __restrict__ sat_tgt,
    float* __restrict__ per_graph, int n, int Bseg)
{
    const int b    = blockIdx.x;
    const int tid  = threadIdx.x;
    const int w    = tid >> 6;                 // wave id: 0 or 1
    const int lane = tid & 63;

    __shared__ int sh_bounds[2];
    {   // wave0 -> lo, wave1 -> hi, concurrent
        int r = wave_lower_bound(batch, n, b + w);
        if (lane == 0) sh_bounds[w] = r;
    }
    __syncthreads();
    const int lo = sh_bounds[0], hi = sh_bounds[1];   // block owns [lo,hi)

    float accb = 0.0f, accc = 0.0f;

    int a0 = (lo + 3) & ~3;                    // first 16B-aligned element
    if (a0 > hi) a0 = hi;
    const int ntiles = (hi - a0) >> 8;         // full TILE=256 tiles
    const int a1     = a0 + (ntiles << 8);

    // scalar head (<=3 elems)
    for (int i = lo + tid; i < a0; i += BLOCK) {
        float mf = (float)mask[i];
        accb += bce_elem(pred[i] * mf, tgt[i]);
        accc += mf;
    }

    // DMA-staged body: wave w owns tiles w, w+2, w+4, ...
    __shared__ float pb[NW][2][TILE];
    __shared__ float tb[NW][2][TILE];
    __shared__ int   mb[NW][2][TILE];

    const float* psrc = pred + a0;
    const float* tsrc = tgt  + a0;
    const int*   msrc = mask + a0;
    const int loff = lane << 2;                // this lane's element offset in tile

    const int myntiles = (ntiles > w) ? ((ntiles - w + 1) >> 1) : 0;

    if (myntiles > 0) {                        // prologue: DMA tile 0 into buf 0
        const int e = (w << 8) + loff;
        GLD16(psrc + e, &pb[w][0][0]);
        GLD16(tsrc + e, &tb[w][0][0]);
        GLD16(msrc + e, &mb[w][0][0]);
    }
    for (int j = 0; j < myntiles; ++j) {
        const int jn = j + 1;
        if (jn < myntiles) {                   // issue next tile, keep 3 in flight
            const int tn = w + (jn << 1);
            const int e  = (tn << 8) + loff;
            const int nb = jn & 1;
            GLD16(psrc + e, &pb[w][nb][0]);
            GLD16(tsrc + e, &tb[w][nb][0]);
            GLD16(msrc + e, &mb[w][nb][0]);
            asm volatile("s_waitcnt vmcnt(3)" ::: "memory");   // tile j landed
        } else {
            asm volatile("s_waitcnt vmcnt(0)" ::: "memory");   // drain last tile
        }
        __builtin_amdgcn_sched_barrier(0);     // no LDS read hoists above the wait
        const int bf = j & 1;
        fx4 p = *(const fx4*)&pb[w][bf][loff];
        fx4 t = *(const fx4*)&tb[w][bf][loff];
        const int* mm = &mb[w][bf][loff];
        float m0 = (float)mm[0], m1 = (float)mm[1],
              m2 = (float)mm[2], m3 = (float)mm[3];
        accb += bce_elem(p[0] * m0, t[0]);  accc += m0;
        accb += bce_elem(p[1] * m1, t[1]);  accc += m1;
        accb += bce_elem(p[2] * m2, t[2]);  accc += m2;
        accb += bce_elem(p[3] * m3, t[3]);  accc += m3;
        __builtin_amdgcn_sched_barrier(0);     // reads/uses stay in this region
    }

    // scalar tail (up to TILE-1 + 3 elems)
    for (int i = a1 + tid; i < hi; i += BLOCK) {
        float mf = (float)mask[i];
        accb += bce_elem(pred[i] * mf, tgt[i]);
        accc += mf;
    }

    // block reduction: wave shfl -> LDS -> thread 0
    #pragma unroll
    for (int o = 32; o > 0; o >>= 1) {
        accb += __shfl_xor(accb, o);
        accc += __shfl_xor(accc, o);
    }
    __shared__ float wb[NW], wc[NW];
    if (lane == 0) { wb[w] = accb; wc[w] = accc; }
    __syncthreads();
    if (tid == 0) {
        float sb = wb[0] + wb[1];
        float sc = wc[0] + wc[1];
        float pg = (sc > 0.0f) ? sb / fmaxf(sc, 1.0f) : 0.0f;
        // fold this graph's share of the sat-BCE mean*L1 term; every b covered once
        pg += bce_elem(sat_pred[b], sat_tgt[b]) * ((1.0f / 50.0f) / (float)Bseg);
        per_graph[b] = pg;                     // plain store: no atomics, no fences
    }
}

__global__ __launch_bounds__(256) void sum_kernel(
    const float* __restrict__ per_graph, float* __restrict__ out, int Bseg)
{
    float local = 0.0f;
    for (int i = threadIdx.x; i < Bseg; i += 256) local += per_graph[i];
    #pragma unroll
    for (int o = 32; o > 0; o >>= 1) local += __shfl_xor(local, o);
    __shared__ float ws[4];
    if ((threadIdx.x & 63) == 0) ws[threadIdx.x >> 6] = local;
    __syncthreads();
    if (threadIdx.x == 0) out[0] = ws[0] + ws[1] + ws[2] + ws[3];
}

extern "C" void kernel_launch(void* const* d_in, const int* in_sizes, int n_in,
                              void* d_out, int out_size, void* d_ws, size_t ws_size,
                              hipStream_t stream) {
    const float* y_mus_pred = (const float*)d_in[0];
    const float* y_mus      = (const float*)d_in[1];
    const float* y_sat_pred = (const float*)d_in[2];
    const float* y_sat      = (const float*)d_in[3];
    const int*   batch      = (const int*)d_in[4];
    const int*   mask       = (const int*)d_in[5];

    const int n    = in_sizes[0];
    const int Bseg = in_sizes[2];

    float* per_graph = (float*)d_ws;   // Bseg floats; every slot written each launch

    seg_kernel<<<Bseg, BLOCK, 0, stream>>>(
        y_mus_pred, y_mus, batch, mask, y_sat_pred, y_sat, per_graph, n, Bseg);
    sum_kernel<<<1, 256, 0, stream>>>(per_graph, (float*)d_out, Bseg);
}